// Round 1
// baseline (982.723 us; speedup 1.0000x reference)
//
#include <hip/hip_runtime.h>
#include <stdint.h>

#define S_TOK 16384
#define M_DIM 512
#define E_EXP 16
#define D_OUT 256
#define H1D 500
#define H2D 500
#define H3D 1000

typedef float f32x4 __attribute__((ext_vector_type(4)));
typedef short s16x8 __attribute__((ext_vector_type(8)));

__device__ __forceinline__ unsigned short f2bf(float f) {
  unsigned int u = __float_as_uint(f);
  u += 0x7fffu + ((u >> 16) & 1u);
  return (unsigned short)(u >> 16);
}

struct TokenRec { int i1, i2; float g1, g2; };

// ---------------- init: zero final_output region + small accumulators ----------------
__global__ __launch_bounds__(256) void k_init(float* __restrict__ out0,
                                              unsigned int* __restrict__ counts,
                                              unsigned int* __restrict__ cursor,
                                              float* __restrict__ proxy) {
  int idx = blockIdx.x * 256 + threadIdx.x;        // grid covers S*D/4 exactly
  f32x4 z = {0.f, 0.f, 0.f, 0.f};
  *(f32x4*)&out0[(size_t)idx * 4] = z;
  if (blockIdx.x == 0 && threadIdx.x < E_EXP) {
    counts[threadIdx.x] = 0u;
    cursor[threadIdx.x] = 0u;
    proxy[threadIdx.x] = 0.f;
  }
}

// ---------------- router: logits (f64 accum), softmax, top-2, select0, stats ----------
__global__ __launch_bounds__(256) void k_router(const float* __restrict__ x,
                                                const float* __restrict__ noise,
                                                const float* __restrict__ Wr,
                                                float* __restrict__ sel_out,
                                                TokenRec* __restrict__ te,
                                                unsigned int* __restrict__ counts,
                                                float* __restrict__ proxy) {
  __shared__ float wr[E_EXP * M_DIM];     // 32 KB
  __shared__ double lg[4][E_EXP];
  __shared__ float bproxy[E_EXP];
  int t = threadIdx.x;
  for (int i = t; i < E_EXP * M_DIM; i += 256) wr[i] = Wr[i];
  if (t < E_EXP) bproxy[t] = 0.f;
  __syncthreads();

  int w = t >> 6, l = t & 63;
  int s = blockIdx.x * 4 + w;

  float xv[8];
#pragma unroll
  for (int j = 0; j < 8; j++) xv[j] = x[(size_t)s * M_DIM + l + 64 * j];

  double lgt[E_EXP];
#pragma unroll
  for (int e = 0; e < E_EXP; e++) {
    double a = 0.0;
#pragma unroll
    for (int j = 0; j < 8; j++) a += (double)xv[j] * (double)wr[e * M_DIM + l + 64 * j];
#pragma unroll
    for (int off = 32; off >= 1; off >>= 1) a += __shfl_xor(a, off, 64);
    lgt[e] = a;
  }
  if (l == 0) {
#pragma unroll
    for (int e = 0; e < E_EXP; e++) lg[w][e] = lgt[e] + (double)noise[(size_t)s * E_EXP + e];
  }
  __syncthreads();

  if (l < E_EXP) {
    double v = lg[w][l];
    double mx = v;
#pragma unroll
    for (int off = 8; off >= 1; off >>= 1) { double o = __shfl_xor(mx, off, 16); mx = (o > mx) ? o : mx; }
    double p = exp(v - mx);
    double sum = p;
#pragma unroll
    for (int off = 8; off >= 1; off >>= 1) sum += __shfl_xor(sum, off, 16);
    float sel = (float)(p / sum);

    // top-2 with smaller-index tiebreak: key = upper bits of double(p) | (255 - lane)
    unsigned long long pb = __double_as_longlong(p);  // p>0 -> monotonic as uint64
    unsigned long long key = (pb & ~0xFFull) | (unsigned long long)(255 - l);
    unsigned long long k1 = key;
#pragma unroll
    for (int off = 8; off >= 1; off >>= 1) { unsigned long long o = __shfl_xor(k1, off, 16); k1 = (o > k1) ? o : k1; }
    int i1 = 255 - (int)(k1 & 0xFFull);
    unsigned long long key2 = (l == i1) ? 0ull : key;
    unsigned long long k2 = key2;
#pragma unroll
    for (int off = 8; off >= 1; off >>= 1) { unsigned long long o = __shfl_xor(k2, off, 16); k2 = (o > k2) ? o : k2; }
    int i2 = 255 - (int)(k2 & 0xFFull);

    double p1 = __shfl(p, i1, 16);
    double p2 = __shfl(p, i2, 16);
    double inv = 1.0 / (p1 + p2);

    sel_out[(size_t)s * E_EXP + l] = (l == i1 || l == i2) ? 1.f : 0.f;
    atomicAdd(&bproxy[l], sel);
    if (l == 0) {
      TokenRec r; r.i1 = i1; r.i2 = i2; r.g1 = (float)(p1 * inv); r.g2 = (float)(p2 * inv);
      te[s] = r;
      atomicAdd(&counts[i1], 1u);
      atomicAdd(&counts[i2], 1u);
    }
  }
  __syncthreads();
  if (t < E_EXP) atomicAdd(&proxy[t], bproxy[t]);
}

// ---------------- prefix over 16 counts + balance loss ----------------
__global__ void k_prefix_loss(const unsigned int* __restrict__ counts,
                              unsigned int* __restrict__ offsets,
                              const float* __restrict__ proxy,
                              float* __restrict__ out_loss) {
  if (threadIdx.x == 0 && blockIdx.x == 0) {
    unsigned int acc = 0; float ls = 0.f;
    for (int e = 0; e < E_EXP; e++) {
      offsets[e] = acc;
      acc += counts[e];
      ls += proxy[e] * (float)counts[e];
    }
    out_loss[0] = ls * ((float)E_EXP / ((float)S_TOK * (float)S_TOK));
    out_loss[1] = 0.f;
  }
}

// ---------------- build compact slot lists ----------------
__global__ __launch_bounds__(256) void k_listbuild(const TokenRec* __restrict__ te,
                                                   const unsigned int* __restrict__ offsets,
                                                   unsigned int* __restrict__ cursor,
                                                   int* __restrict__ slot_token,
                                                   float* __restrict__ slot_gate) {
  int s = blockIdx.x * 256 + threadIdx.x;
  TokenRec r = te[s];
  unsigned int p1 = atomicAdd(&cursor[r.i1], 1u);
  int sl1 = (int)(offsets[r.i1] + p1);
  slot_token[sl1] = s; slot_gate[sl1] = r.g1;
  unsigned int p2 = atomicAdd(&cursor[r.i2], 1u);
  int sl2 = (int)(offsets[r.i2] + p2);
  slot_token[sl2] = s; slot_gate[sl2] = r.g2;
}

// ---------------- gather x rows -> bf16 compact activations ----------------
__global__ __launch_bounds__(256) void k_gather(const float* __restrict__ x,
                                                const int* __restrict__ slot_token,
                                                unsigned short* __restrict__ xg) {
  int idx = blockIdx.x * 256 + threadIdx.x;  // 32768*128 total
  int row = idx >> 7, q = idx & 127;
  int tkn = slot_token[row];
  f32x4 v = *(const f32x4*)&x[(size_t)tkn * M_DIM + q * 4];
  ushort4 o;
  o.x = f2bf(v.x); o.y = f2bf(v.y); o.z = f2bf(v.z); o.w = f2bf(v.w);
  *(ushort4*)&xg[(size_t)row * 512 + q * 4] = o;
}

// ---------------- weight convert: f32 [E][Kr][Nr] -> bf16 transposed padded [E][Np][Kp]
__global__ __launch_bounds__(256) void k_convw(const float* __restrict__ src,
                                               unsigned short* __restrict__ dst,
                                               int Kr, int Nr, int Kp, int Np) {
  __shared__ float tile[64][65];
  int e = blockIdx.z;
  int k0 = blockIdx.x * 64, n0 = blockIdx.y * 64;
  int t = threadIdx.x;
  int cx = t & 63, ry = t >> 6;  // ry 0..3
  const float* sp = src + (size_t)e * Kr * Nr;
#pragma unroll
  for (int i = 0; i < 16; i++) {
    int k = k0 + ry + i * 4, n = n0 + cx;
    float v = (k < Kr && n < Nr) ? sp[(size_t)k * Nr + n] : 0.f;
    tile[ry + i * 4][cx] = v;
  }
  __syncthreads();
  unsigned short* dp = dst + (size_t)e * Np * Kp;
#pragma unroll
  for (int i = 0; i < 16; i++) {
    int nl = ry + i * 4, kl = cx;
    dp[(size_t)(n0 + nl) * Kp + k0 + kl] = f2bf(tile[kl][nl]);
  }
}

// ---------------- grouped GEMM, mid layers: out = relu(in @ W + b), bf16 out, pad-fill 0
__global__ __launch_bounds__(256) void k_gemm_mid(const unsigned short* __restrict__ in,
                                                  const unsigned short* __restrict__ wt,
                                                  const float* __restrict__ bias,
                                                  unsigned short* __restrict__ out,
                                                  const unsigned int* __restrict__ offsets,
                                                  const unsigned int* __restrict__ counts,
                                                  int KP, int NP, int NREAL) {
  int e = blockIdx.z;
  int n_e = (int)counts[e];
  int base = (int)offsets[e];
  int bn = blockIdx.y;
  __shared__ unsigned short As[64 * 40];
  __shared__ unsigned short Bs[64 * 40];
  int t = threadIdx.x;
  int wv = t >> 6, l = t & 63;
  int r_st = t >> 2, seg = t & 3;
  int lr = l & 15, lq = l >> 4;

  for (int bm = blockIdx.x; bm * 64 < n_e; bm += gridDim.x) {
    f32x4 acc0 = {0,0,0,0}, acc1 = {0,0,0,0}, acc2 = {0,0,0,0}, acc3 = {0,0,0,0};
    const unsigned short* arow = in + (size_t)(base + bm * 64 + r_st) * KP + seg * 8;
    const unsigned short* brow = wt + (size_t)e * NP * KP + (size_t)(bn * 64 + r_st) * KP + seg * 8;
    for (int k0 = 0; k0 < KP; k0 += 32) {
      uint4 av = *(const uint4*)(arow + k0);
      uint4 bv = *(const uint4*)(brow + k0);
      __syncthreads();
      *(uint4*)&As[r_st * 40 + seg * 8] = av;
      *(uint4*)&Bs[r_st * 40 + seg * 8] = bv;
      __syncthreads();
      s16x8 af = *(const s16x8*)&As[(wv * 16 + lr) * 40 + lq * 8];
      s16x8 b0 = *(const s16x8*)&Bs[(0 * 16 + lr) * 40 + lq * 8];
      s16x8 b1 = *(const s16x8*)&Bs[(1 * 16 + lr) * 40 + lq * 8];
      s16x8 b2 = *(const s16x8*)&Bs[(2 * 16 + lr) * 40 + lq * 8];
      s16x8 b3 = *(const s16x8*)&Bs[(3 * 16 + lr) * 40 + lq * 8];
      acc0 = __builtin_amdgcn_mfma_f32_16x16x32_bf16(af, b0, acc0, 0, 0, 0);
      acc1 = __builtin_amdgcn_mfma_f32_16x16x32_bf16(af, b1, acc1, 0, 0, 0);
      acc2 = __builtin_amdgcn_mfma_f32_16x16x32_bf16(af, b2, acc2, 0, 0, 0);
      acc3 = __builtin_amdgcn_mfma_f32_16x16x32_bf16(af, b3, acc3, 0, 0, 0);
    }
#pragma unroll
    for (int nt = 0; nt < 4; nt++) {
      f32x4 a = (nt == 0) ? acc0 : (nt == 1) ? acc1 : (nt == 2) ? acc2 : acc3;
      int col = bn * 64 + nt * 16 + lr;
      float bv_ = (col < NREAL) ? bias[(size_t)e * NREAL + col] : 0.f;
#pragma unroll
      for (int reg = 0; reg < 4; reg++) {
        int r = bm * 64 + wv * 16 + lq * 4 + reg;
        if (r < n_e) {
          float v = (col < NREAL) ? fmaxf(a[reg] + bv_, 0.f) : 0.f;
          out[(size_t)(base + r) * NP + col] = f2bf(v);
        }
      }
    }
  }
}

// ---------------- grouped GEMM, final layer: scatter gate*(h3@W4+b4) via atomicAdd ----
__global__ __launch_bounds__(256) void k_gemm_fin(const unsigned short* __restrict__ in,
                                                  const unsigned short* __restrict__ wt,
                                                  const float* __restrict__ bias,
                                                  float* __restrict__ dout,
                                                  const unsigned int* __restrict__ offsets,
                                                  const unsigned int* __restrict__ counts,
                                                  const int* __restrict__ slot_token,
                                                  const float* __restrict__ slot_gate) {
  const int KP = 1024, NP = 256;
  int e = blockIdx.z;
  int n_e = (int)counts[e];
  int base = (int)offsets[e];
  int bn = blockIdx.y;
  __shared__ unsigned short As[64 * 40];
  __shared__ unsigned short Bs[64 * 40];
  int t = threadIdx.x;
  int wv = t >> 6, l = t & 63;
  int r_st = t >> 2, seg = t & 3;
  int lr = l & 15, lq = l >> 4;

  for (int bm = blockIdx.x; bm * 64 < n_e; bm += gridDim.x) {
    f32x4 acc0 = {0,0,0,0}, acc1 = {0,0,0,0}, acc2 = {0,0,0,0}, acc3 = {0,0,0,0};
    const unsigned short* arow = in + (size_t)(base + bm * 64 + r_st) * KP + seg * 8;
    const unsigned short* brow = wt + (size_t)e * NP * KP + (size_t)(bn * 64 + r_st) * KP + seg * 8;
    for (int k0 = 0; k0 < KP; k0 += 32) {
      uint4 av = *(const uint4*)(arow + k0);
      uint4 bv = *(const uint4*)(brow + k0);
      __syncthreads();
      *(uint4*)&As[r_st * 40 + seg * 8] = av;
      *(uint4*)&Bs[r_st * 40 + seg * 8] = bv;
      __syncthreads();
      s16x8 af = *(const s16x8*)&As[(wv * 16 + lr) * 40 + lq * 8];
      s16x8 b0 = *(const s16x8*)&Bs[(0 * 16 + lr) * 40 + lq * 8];
      s16x8 b1 = *(const s16x8*)&Bs[(1 * 16 + lr) * 40 + lq * 8];
      s16x8 b2 = *(const s16x8*)&Bs[(2 * 16 + lr) * 40 + lq * 8];
      s16x8 b3 = *(const s16x8*)&Bs[(3 * 16 + lr) * 40 + lq * 8];
      acc0 = __builtin_amdgcn_mfma_f32_16x16x32_bf16(af, b0, acc0, 0, 0, 0);
      acc1 = __builtin_amdgcn_mfma_f32_16x16x32_bf16(af, b1, acc1, 0, 0, 0);
      acc2 = __builtin_amdgcn_mfma_f32_16x16x32_bf16(af, b2, acc2, 0, 0, 0);
      acc3 = __builtin_amdgcn_mfma_f32_16x16x32_bf16(af, b3, acc3, 0, 0, 0);
    }
#pragma unroll
    for (int reg = 0; reg < 4; reg++) {
      int r = bm * 64 + wv * 16 + lq * 4 + reg;
      if (r < n_e) {
        int gr = base + r;
        int tk = slot_token[gr];
        float g = slot_gate[gr];
#pragma unroll
        for (int nt = 0; nt < 4; nt++) {
          f32x4 a = (nt == 0) ? acc0 : (nt == 1) ? acc1 : (nt == 2) ? acc2 : acc3;
          int col = bn * 64 + nt * 16 + lr;
          float v = a[reg] + bias[(size_t)e * 256 + col];
          atomicAdd(&dout[(size_t)tk * D_OUT + col], g * v);
        }
      }
    }
  }
}

extern "C" void kernel_launch(void* const* d_in, const int* in_sizes, int n_in,
                              void* d_out, int out_size, void* d_ws, size_t ws_size,
                              hipStream_t stream) {
  const float* x    = (const float*)d_in[0];
  const float* nois = (const float*)d_in[1];
  const float* Wr   = (const float*)d_in[2];
  const float* W1   = (const float*)d_in[3];
  const float* b1   = (const float*)d_in[4];
  const float* W2   = (const float*)d_in[5];
  const float* b2   = (const float*)d_in[6];
  const float* W3   = (const float*)d_in[7];
  const float* b3   = (const float*)d_in[8];
  const float* W4   = (const float*)d_in[9];
  const float* b4   = (const float*)d_in[10];
  float* out = (float*)d_out;

  char* w = (char*)d_ws;
  // ws layout (all 256B aligned); total ~118 MB
  unsigned short* actA = (unsigned short*)(w + 0);             // 32768*1024 bf16 = 67108864 B
  unsigned short* actB = (unsigned short*)(w + 67108864);      // 32768*512 bf16  = 33554432 B
  unsigned short* Wt   = (unsigned short*)(w + 100663296);     // <=16*512*1024 bf16 = 16777216 B
  int*            slot_token = (int*)(w + 117440512);          // 131072 B
  float*          slot_gate  = (float*)(w + 117571584);        // 131072 B
  TokenRec*       te         = (TokenRec*)(w + 117702656);     // 262144 B
  unsigned int*   counts  = (unsigned int*)(w + 117964800);
  unsigned int*   cursor  = (unsigned int*)(w + 117964864);
  unsigned int*   offsets = (unsigned int*)(w + 117964928);
  float*          proxy   = (float*)(w + 117964992);

  float* sel_out  = out + (size_t)S_TOK * D_OUT;
  float* loss_out = out + (size_t)S_TOK * D_OUT + (size_t)S_TOK * E_EXP;

  k_init<<<dim3((S_TOK * D_OUT) / 1024), dim3(256), 0, stream>>>(out, counts, cursor, proxy);
  k_router<<<dim3(S_TOK / 4), dim3(256), 0, stream>>>(x, nois, Wr, sel_out, te, counts, proxy);
  k_prefix_loss<<<dim3(1), dim3(64), 0, stream>>>(counts, offsets, proxy, loss_out);
  k_listbuild<<<dim3(S_TOK / 256), dim3(256), 0, stream>>>(te, offsets, cursor, slot_token, slot_gate);
  k_gather<<<dim3((2 * S_TOK * 128) / 256), dim3(256), 0, stream>>>(x, slot_token, actB);

  // Layer 1: [*,512] @ [512,500] -> relu -> actA (stride 512)
  k_convw<<<dim3(8, 8, E_EXP), dim3(256), 0, stream>>>(W1, Wt, 512, H1D, 512, 512);
  k_gemm_mid<<<dim3(64, 8, E_EXP), dim3(256), 0, stream>>>(actB, Wt, b1, actA, offsets, counts, 512, 512, H1D);
  // Layer 2: [*,500] @ [500,500] -> relu -> actB (stride 512)
  k_convw<<<dim3(8, 8, E_EXP), dim3(256), 0, stream>>>(W2, Wt, H1D, H2D, 512, 512);
  k_gemm_mid<<<dim3(64, 8, E_EXP), dim3(256), 0, stream>>>(actA, Wt, b2, actB, offsets, counts, 512, 512, H2D);
  // Layer 3: [*,500] @ [500,1000] -> relu -> actA (stride 1024)
  k_convw<<<dim3(8, 16, E_EXP), dim3(256), 0, stream>>>(W3, Wt, H2D, H3D, 512, 1024);
  k_gemm_mid<<<dim3(64, 16, E_EXP), dim3(256), 0, stream>>>(actB, Wt, b3, actA, offsets, counts, 512, 1024, H3D);
  // Layer 4: [*,1000] @ [1000,256] -> scatter gate-weighted into out
  k_convw<<<dim3(16, 4, E_EXP), dim3(256), 0, stream>>>(W4, Wt, H3D, D_OUT, 1024, 256);
  k_gemm_fin<<<dim3(64, 4, E_EXP), dim3(256), 0, stream>>>(actA, Wt, b4, out, offsets, counts, slot_token, slot_gate);

  (void)in_sizes; (void)n_in; (void)out_size; (void)ws_size;
}

// Round 2
// 542.034 us; speedup vs baseline: 1.8130x; 1.8130x over previous
//
#include <hip/hip_runtime.h>
#include <stdint.h>

#define S_TOK 16384
#define M_DIM 512
#define E_EXP 16
#define D_OUT 256
#define H1D 500
#define H2D 500
#define H3D 1000

typedef float f32x4 __attribute__((ext_vector_type(4)));
typedef short s16x8 __attribute__((ext_vector_type(8)));

__device__ __forceinline__ unsigned short f2bf(float f) {
  unsigned int u = __float_as_uint(f);
  u += 0x7fffu + ((u >> 16) & 1u);
  return (unsigned short)(u >> 16);
}

struct TokenRec { int i1, i2; float g1, g2; };

// ---------------- init: zero final_output + cursor ----------------
__global__ __launch_bounds__(256) void k_init(float* __restrict__ out0,
                                              unsigned int* __restrict__ cursor) {
  int idx = blockIdx.x * 256 + threadIdx.x;        // grid covers S*D/4 exactly
  f32x4 z = {0.f, 0.f, 0.f, 0.f};
  *(f32x4*)&out0[(size_t)idx * 4] = z;
  if (blockIdx.x == 0 && threadIdx.x < E_EXP) cursor[threadIdx.x] = 0u;
}

// ---------------- router v2: lane-parallel experts, f64 accum, no global atomics ------
// 64 lanes = 16 experts x 4 tokens; block=256 handles 16 tokens.
__global__ __launch_bounds__(256) void k_router(const float* __restrict__ x,
                                                const float* __restrict__ noise,
                                                const float* __restrict__ Wr,
                                                float* __restrict__ sel_out,
                                                float* __restrict__ sel_buf,
                                                TokenRec* __restrict__ te) {
  __shared__ float wr[E_EXP * 516];   // pad 516: 2-way LDS aliasing only (free)
  int t = threadIdx.x;
  for (int i = t; i < E_EXP * M_DIM; i += 256) {
    int e = i >> 9, m = i & 511;
    wr[e * 516 + m] = Wr[i];
  }
  __syncthreads();

  int wv = t >> 6, l = t & 63;
  int e = l & 15, tg = l >> 4;                  // expert, token-slot in wave
  int s = blockIdx.x * 16 + wv * 4 + tg;        // token id

  const float* xr = x + (size_t)s * M_DIM;
  const float* wre = &wr[e * 516];
  double a0 = 0.0, a1 = 0.0, a2 = 0.0, a3 = 0.0;
#pragma unroll 4
  for (int m = 0; m < M_DIM; m += 4) {
    f32x4 xv = *(const f32x4*)(xr + m);         // broadcast among 16 lanes (same tg)
    f32x4 wv4 = *(const f32x4*)(wre + m);
    a0 += (double)xv.x * (double)wv4.x;
    a1 += (double)xv.y * (double)wv4.y;
    a2 += (double)xv.z * (double)wv4.z;
    a3 += (double)xv.w * (double)wv4.w;
  }
  double a = (a0 + a1) + (a2 + a3);
  a += (double)noise[(size_t)s * E_EXP + e];    // lanes consecutive: coalesced

  // softmax over 16-lane group
  double mx = a;
#pragma unroll
  for (int off = 8; off >= 1; off >>= 1) { double o = __shfl_xor(mx, off, 64); mx = (o > mx) ? o : mx; }
  double p = exp(a - mx);
  double sum = p;
#pragma unroll
  for (int off = 8; off >= 1; off >>= 1) sum += __shfl_xor(sum, off, 64);
  sel_buf[(size_t)s * E_EXP + e] = (float)(p / sum);

  // top-2 (smaller-index tiebreak): key = high bits of f64 p | (255 - e)
  unsigned long long pb = __double_as_longlong(p);
  unsigned long long key = (pb & ~0xFFull) | (unsigned long long)(255 - e);
  unsigned long long k1 = key;
#pragma unroll
  for (int off = 8; off >= 1; off >>= 1) { unsigned long long o = __shfl_xor(k1, off, 64); k1 = (o > k1) ? o : k1; }
  int i1 = 255 - (int)(k1 & 0xFFull);
  unsigned long long key2 = (e == i1) ? 0ull : key;
  unsigned long long k2 = key2;
#pragma unroll
  for (int off = 8; off >= 1; off >>= 1) { unsigned long long o = __shfl_xor(k2, off, 64); k2 = (o > k2) ? o : k2; }
  int i2 = 255 - (int)(k2 & 0xFFull);

  double p1 = __shfl(p, tg * 16 + i1, 64);
  double p2 = __shfl(p, tg * 16 + i2, 64);

  sel_out[(size_t)s * E_EXP + e] = (e == i1 || e == i2) ? 1.f : 0.f;
  if (e == 0) {
    double inv = 1.0 / (p1 + p2);
    TokenRec r; r.i1 = i1; r.i2 = i2; r.g1 = (float)(p1 * inv); r.g2 = (float)(p2 * inv);
    te[s] = r;
  }
}

// ---------------- stats: per-block proxy partial sums + histogram, no contended atomics
__global__ __launch_bounds__(256) void k_stats(const float* __restrict__ sel_buf,
                                               const TokenRec* __restrict__ te,
                                               float* __restrict__ partials) {  // [16][32]
  __shared__ float psum[256];
  __shared__ unsigned int hist[E_EXP];
  int t = threadIdx.x, b = blockIdx.x;
  if (t < E_EXP) hist[t] = 0u;
  __syncthreads();
  int e = t & 15, rg = t >> 4;
  int base = b * 1024;
  float acc = 0.f;
#pragma unroll 4
  for (int i = 0; i < 64; i++)
    acc += sel_buf[(size_t)(base + i * 16 + rg) * E_EXP + e];
  for (int i = t; i < 1024; i += 256) {
    TokenRec r = te[base + i];
    atomicAdd(&hist[r.i1], 1u);   // LDS atomics
    atomicAdd(&hist[r.i2], 1u);
  }
  psum[t] = acc;
  __syncthreads();
  if (t < E_EXP) {
    float v = 0.f;
#pragma unroll
    for (int rg2 = 0; rg2 < 16; rg2++) v += psum[rg2 * 16 + t];
    partials[b * 32 + t] = v;
    partials[b * 32 + 16 + t] = (float)hist[t];
  }
}

// ---------------- reduce partials -> counts/offsets + balance loss ----------------
__global__ void k_prefix_loss(const float* __restrict__ partials,
                              unsigned int* __restrict__ counts,
                              unsigned int* __restrict__ offsets,
                              float* __restrict__ out_loss) {
  __shared__ float pr[E_EXP];
  __shared__ unsigned int cn[E_EXP];
  int t = threadIdx.x;
  if (t < E_EXP) {
    float p = 0.f, c = 0.f;
    for (int b = 0; b < 16; b++) { p += partials[b * 32 + t]; c += partials[b * 32 + 16 + t]; }
    pr[t] = p; cn[t] = (unsigned int)(c + 0.5f);
  }
  __syncthreads();
  if (t == 0) {
    unsigned int acc = 0; float ls = 0.f;
    for (int e = 0; e < E_EXP; e++) {
      counts[e] = cn[e];
      offsets[e] = acc;
      acc += cn[e];
      ls += pr[e] * (float)cn[e];
    }
    out_loss[0] = ls * ((float)E_EXP / ((float)S_TOK * (float)S_TOK));
    out_loss[1] = 0.f;
  }
}

// ---------------- listbuild v2: block-level reservation (256 global atomics total) ----
__global__ __launch_bounds__(256) void k_listbuild(const TokenRec* __restrict__ te,
                                                   const unsigned int* __restrict__ offsets,
                                                   unsigned int* __restrict__ cursor,
                                                   int* __restrict__ slot_token,
                                                   float* __restrict__ slot_gate) {
  __shared__ unsigned int lhist[E_EXP];
  __shared__ unsigned int lbase[E_EXP];
  __shared__ unsigned int lcur[E_EXP];
  int t = threadIdx.x, b = blockIdx.x;
  int base = b * 1024;
  if (t < E_EXP) lhist[t] = 0u;
  __syncthreads();
  for (int i = t; i < 1024; i += 256) {
    TokenRec r = te[base + i];
    atomicAdd(&lhist[r.i1], 1u);
    atomicAdd(&lhist[r.i2], 1u);
  }
  __syncthreads();
  if (t < E_EXP) {
    lbase[t] = offsets[t] + atomicAdd(&cursor[t], lhist[t]);  // one global atomic / expert / block
    lcur[t] = 0u;
  }
  __syncthreads();
  for (int i = t; i < 1024; i += 256) {
    int s = base + i;
    TokenRec r = te[s];
    unsigned int p1 = atomicAdd(&lcur[r.i1], 1u);
    int sl1 = (int)(lbase[r.i1] + p1);
    slot_token[sl1] = s; slot_gate[sl1] = r.g1;
    unsigned int p2 = atomicAdd(&lcur[r.i2], 1u);
    int sl2 = (int)(lbase[r.i2] + p2);
    slot_token[sl2] = s; slot_gate[sl2] = r.g2;
  }
}

// ---------------- gather x rows -> bf16 compact activations ----------------
__global__ __launch_bounds__(256) void k_gather(const float* __restrict__ x,
                                                const int* __restrict__ slot_token,
                                                unsigned short* __restrict__ xg) {
  int idx = blockIdx.x * 256 + threadIdx.x;  // 32768*128 total
  int row = idx >> 7, q = idx & 127;
  int tkn = slot_token[row];
  f32x4 v = *(const f32x4*)&x[(size_t)tkn * M_DIM + q * 4];
  ushort4 o;
  o.x = f2bf(v.x); o.y = f2bf(v.y); o.z = f2bf(v.z); o.w = f2bf(v.w);
  *(ushort4*)&xg[(size_t)row * 512 + q * 4] = o;
}

// ---------------- weight convert: f32 [E][Kr][Nr] -> bf16 transposed padded [E][Np][Kp]
__global__ __launch_bounds__(256) void k_convw(const float* __restrict__ src,
                                               unsigned short* __restrict__ dst,
                                               int Kr, int Nr, int Kp, int Np) {
  __shared__ float tile[64][65];
  int e = blockIdx.z;
  int k0 = blockIdx.x * 64, n0 = blockIdx.y * 64;
  int t = threadIdx.x;
  int cx = t & 63, ry = t >> 6;  // ry 0..3
  const float* sp = src + (size_t)e * Kr * Nr;
#pragma unroll
  for (int i = 0; i < 16; i++) {
    int k = k0 + ry + i * 4, n = n0 + cx;
    float v = (k < Kr && n < Nr) ? sp[(size_t)k * Nr + n] : 0.f;
    tile[ry + i * 4][cx] = v;
  }
  __syncthreads();
  unsigned short* dp = dst + (size_t)e * Np * Kp;
#pragma unroll
  for (int i = 0; i < 16; i++) {
    int nl = ry + i * 4, kl = cx;
    dp[(size_t)(n0 + nl) * Kp + k0 + kl] = f2bf(tile[kl][nl]);
  }
}

// ---------------- grouped GEMM, mid layers: out = relu(in @ W + b), bf16 out ----------
__global__ __launch_bounds__(256) void k_gemm_mid(const unsigned short* __restrict__ in,
                                                  const unsigned short* __restrict__ wt,
                                                  const float* __restrict__ bias,
                                                  unsigned short* __restrict__ out,
                                                  const unsigned int* __restrict__ offsets,
                                                  const unsigned int* __restrict__ counts,
                                                  int KP, int NP, int NREAL) {
  int e = blockIdx.z;
  int n_e = (int)counts[e];
  int base = (int)offsets[e];
  int bn = blockIdx.y;
  __shared__ unsigned short As[64 * 40];
  __shared__ unsigned short Bs[64 * 40];
  int t = threadIdx.x;
  int wv = t >> 6, l = t & 63;
  int r_st = t >> 2, seg = t & 3;
  int lr = l & 15, lq = l >> 4;

  for (int bm = blockIdx.x; bm * 64 < n_e; bm += gridDim.x) {
    f32x4 acc0 = {0,0,0,0}, acc1 = {0,0,0,0}, acc2 = {0,0,0,0}, acc3 = {0,0,0,0};
    const unsigned short* arow = in + (size_t)(base + bm * 64 + r_st) * KP + seg * 8;
    const unsigned short* brow = wt + (size_t)e * NP * KP + (size_t)(bn * 64 + r_st) * KP + seg * 8;
    for (int k0 = 0; k0 < KP; k0 += 32) {
      uint4 av = *(const uint4*)(arow + k0);
      uint4 bv = *(const uint4*)(brow + k0);
      __syncthreads();
      *(uint4*)&As[r_st * 40 + seg * 8] = av;
      *(uint4*)&Bs[r_st * 40 + seg * 8] = bv;
      __syncthreads();
      s16x8 af = *(const s16x8*)&As[(wv * 16 + lr) * 40 + lq * 8];
      s16x8 b0 = *(const s16x8*)&Bs[(0 * 16 + lr) * 40 + lq * 8];
      s16x8 b1 = *(const s16x8*)&Bs[(1 * 16 + lr) * 40 + lq * 8];
      s16x8 b2 = *(const s16x8*)&Bs[(2 * 16 + lr) * 40 + lq * 8];
      s16x8 b3 = *(const s16x8*)&Bs[(3 * 16 + lr) * 40 + lq * 8];
      acc0 = __builtin_amdgcn_mfma_f32_16x16x32_bf16(af, b0, acc0, 0, 0, 0);
      acc1 = __builtin_amdgcn_mfma_f32_16x16x32_bf16(af, b1, acc1, 0, 0, 0);
      acc2 = __builtin_amdgcn_mfma_f32_16x16x32_bf16(af, b2, acc2, 0, 0, 0);
      acc3 = __builtin_amdgcn_mfma_f32_16x16x32_bf16(af, b3, acc3, 0, 0, 0);
    }
#pragma unroll
    for (int nt = 0; nt < 4; nt++) {
      f32x4 a = (nt == 0) ? acc0 : (nt == 1) ? acc1 : (nt == 2) ? acc2 : acc3;
      int col = bn * 64 + nt * 16 + lr;
      float bv_ = (col < NREAL) ? bias[(size_t)e * NREAL + col] : 0.f;
#pragma unroll
      for (int reg = 0; reg < 4; reg++) {
        int r = bm * 64 + wv * 16 + lq * 4 + reg;
        if (r < n_e) {
          float v = (col < NREAL) ? fmaxf(a[reg] + bv_, 0.f) : 0.f;
          out[(size_t)(base + r) * NP + col] = f2bf(v);
        }
      }
    }
  }
}

// ---------------- grouped GEMM, final layer: scatter gate*(h3@W4+b4) via atomicAdd ----
__global__ __launch_bounds__(256) void k_gemm_fin(const unsigned short* __restrict__ in,
                                                  const unsigned short* __restrict__ wt,
                                                  const float* __restrict__ bias,
                                                  float* __restrict__ dout,
                                                  const unsigned int* __restrict__ offsets,
                                                  const unsigned int* __restrict__ counts,
                                                  const int* __restrict__ slot_token,
                                                  const float* __restrict__ slot_gate) {
  const int KP = 1024, NP = 256;
  int e = blockIdx.z;
  int n_e = (int)counts[e];
  int base = (int)offsets[e];
  int bn = blockIdx.y;
  __shared__ unsigned short As[64 * 40];
  __shared__ unsigned short Bs[64 * 40];
  int t = threadIdx.x;
  int wv = t >> 6, l = t & 63;
  int r_st = t >> 2, seg = t & 3;
  int lr = l & 15, lq = l >> 4;

  for (int bm = blockIdx.x; bm * 64 < n_e; bm += gridDim.x) {
    f32x4 acc0 = {0,0,0,0}, acc1 = {0,0,0,0}, acc2 = {0,0,0,0}, acc3 = {0,0,0,0};
    const unsigned short* arow = in + (size_t)(base + bm * 64 + r_st) * KP + seg * 8;
    const unsigned short* brow = wt + (size_t)e * NP * KP + (size_t)(bn * 64 + r_st) * KP + seg * 8;
    for (int k0 = 0; k0 < KP; k0 += 32) {
      uint4 av = *(const uint4*)(arow + k0);
      uint4 bv = *(const uint4*)(brow + k0);
      __syncthreads();
      *(uint4*)&As[r_st * 40 + seg * 8] = av;
      *(uint4*)&Bs[r_st * 40 + seg * 8] = bv;
      __syncthreads();
      s16x8 af = *(const s16x8*)&As[(wv * 16 + lr) * 40 + lq * 8];
      s16x8 b0 = *(const s16x8*)&Bs[(0 * 16 + lr) * 40 + lq * 8];
      s16x8 b1 = *(const s16x8*)&Bs[(1 * 16 + lr) * 40 + lq * 8];
      s16x8 b2 = *(const s16x8*)&Bs[(2 * 16 + lr) * 40 + lq * 8];
      s16x8 b3 = *(const s16x8*)&Bs[(3 * 16 + lr) * 40 + lq * 8];
      acc0 = __builtin_amdgcn_mfma_f32_16x16x32_bf16(af, b0, acc0, 0, 0, 0);
      acc1 = __builtin_amdgcn_mfma_f32_16x16x32_bf16(af, b1, acc1, 0, 0, 0);
      acc2 = __builtin_amdgcn_mfma_f32_16x16x32_bf16(af, b2, acc2, 0, 0, 0);
      acc3 = __builtin_amdgcn_mfma_f32_16x16x32_bf16(af, b3, acc3, 0, 0, 0);
    }
#pragma unroll
    for (int reg = 0; reg < 4; reg++) {
      int r = bm * 64 + wv * 16 + lq * 4 + reg;
      if (r < n_e) {
        int gr = base + r;
        int tk = slot_token[gr];
        float g = slot_gate[gr];
#pragma unroll
        for (int nt = 0; nt < 4; nt++) {
          f32x4 a = (nt == 0) ? acc0 : (nt == 1) ? acc1 : (nt == 2) ? acc2 : acc3;
          int col = bn * 64 + nt * 16 + lr;
          float v = a[reg] + bias[(size_t)e * 256 + col];
          atomicAdd(&dout[(size_t)tk * D_OUT + col], g * v);
        }
      }
    }
  }
}

extern "C" void kernel_launch(void* const* d_in, const int* in_sizes, int n_in,
                              void* d_out, int out_size, void* d_ws, size_t ws_size,
                              hipStream_t stream) {
  const float* x    = (const float*)d_in[0];
  const float* nois = (const float*)d_in[1];
  const float* Wr   = (const float*)d_in[2];
  const float* W1   = (const float*)d_in[3];
  const float* b1   = (const float*)d_in[4];
  const float* W2   = (const float*)d_in[5];
  const float* b2   = (const float*)d_in[6];
  const float* W3   = (const float*)d_in[7];
  const float* b3   = (const float*)d_in[8];
  const float* W4   = (const float*)d_in[9];
  const float* b4   = (const float*)d_in[10];
  float* out = (float*)d_out;

  char* w = (char*)d_ws;
  // ws layout (all 256B aligned); high-water ~118 MB (same as round 1)
  unsigned short* actA = (unsigned short*)(w + 0);             // 32768*1024 bf16 = 67108864 B
  unsigned short* actB = (unsigned short*)(w + 67108864);      // 32768*512 bf16  = 33554432 B
  unsigned short* Wt   = (unsigned short*)(w + 100663296);     // <=16*512*1024 bf16 = 16777216 B
  int*            slot_token = (int*)(w + 117440512);          // 131072 B
  float*          slot_gate  = (float*)(w + 117571584);        // 131072 B
  TokenRec*       te         = (TokenRec*)(w + 117702656);     // 262144 B
  unsigned int*   counts  = (unsigned int*)(w + 117964800);
  unsigned int*   cursor  = (unsigned int*)(w + 117964864);
  unsigned int*   offsets = (unsigned int*)(w + 117964928);
  // transient (dead before GEMM L1 writes actA): overlay on actA region
  float*          sel_buf  = (float*)(w + 0);                  // 16384*16 f32 = 1 MB
  float*          partials = (float*)(w + 1048576);            // 16*32 f32 = 2 KB

  float* sel_out  = out + (size_t)S_TOK * D_OUT;
  float* loss_out = out + (size_t)S_TOK * D_OUT + (size_t)S_TOK * E_EXP;

  k_init<<<dim3((S_TOK * D_OUT) / 1024), dim3(256), 0, stream>>>(out, cursor);
  k_router<<<dim3(S_TOK / 16), dim3(256), 0, stream>>>(x, nois, Wr, sel_out, sel_buf, te);
  k_stats<<<dim3(16), dim3(256), 0, stream>>>(sel_buf, te, partials);
  k_prefix_loss<<<dim3(1), dim3(64), 0, stream>>>(partials, counts, offsets, loss_out);
  k_listbuild<<<dim3(16), dim3(256), 0, stream>>>(te, offsets, cursor, slot_token, slot_gate);
  k_gather<<<dim3((2 * S_TOK * 128) / 256), dim3(256), 0, stream>>>(x, slot_token, actB);

  // Layer 1: [*,512] @ [512,500] -> relu -> actA (stride 512)
  k_convw<<<dim3(8, 8, E_EXP), dim3(256), 0, stream>>>(W1, Wt, 512, H1D, 512, 512);
  k_gemm_mid<<<dim3(64, 8, E_EXP), dim3(256), 0, stream>>>(actB, Wt, b1, actA, offsets, counts, 512, 512, H1D);
  // Layer 2: [*,500] @ [500,500] -> relu -> actB (stride 512)
  k_convw<<<dim3(8, 8, E_EXP), dim3(256), 0, stream>>>(W2, Wt, H1D, H2D, 512, 512);
  k_gemm_mid<<<dim3(64, 8, E_EXP), dim3(256), 0, stream>>>(actA, Wt, b2, actB, offsets, counts, 512, 512, H2D);
  // Layer 3: [*,500] @ [500,1000] -> relu -> actA (stride 1024)
  k_convw<<<dim3(8, 16, E_EXP), dim3(256), 0, stream>>>(W3, Wt, H2D, H3D, 512, 1024);
  k_gemm_mid<<<dim3(64, 16, E_EXP), dim3(256), 0, stream>>>(actB, Wt, b3, actA, offsets, counts, 512, 1024, H3D);
  // Layer 4: [*,1000] @ [1000,256] -> scatter gate-weighted into out
  k_convw<<<dim3(16, 4, E_EXP), dim3(256), 0, stream>>>(W4, Wt, H3D, D_OUT, 1024, 256);
  k_gemm_fin<<<dim3(64, 4, E_EXP), dim3(256), 0, stream>>>(actA, Wt, b4, out, offsets, counts, slot_token, slot_gate);

  (void)in_sizes; (void)n_in; (void)out_size; (void)ws_size;
}